// Round 3
// baseline (130.200 us; speedup 1.0000x reference)
//
#include <hip/hip_runtime.h>

// Problem constants: B=2, L=2048, H=8, D=64, window=32, stride=64
#define Bc 2
#define Lc 2048
#define Hc 8
#define Dc 64
#define TL 16                 // rows per block
#define NT (Lc / TL)          // 128 tiles
#define RHD (Hc * Dc)         // 512 floats between consecutive s rows
#define SP1 65                // stride+1
#define SCALE 0.125f          // 1/sqrt(64)

// DPP-based add of a permuted copy: 1-2 VALU instrs, no DS traffic.
// quad_perm xor1 = 0xB1, xor2 = 0x4E, row_half_mirror = 0x141, row_mirror = 0x140
template <int CTRL>
__device__ __forceinline__ float dpp_add(float x) {
    int p = __builtin_amdgcn_update_dpp(0, __float_as_int(x), CTRL, 0xF, 0xF, true);
    return x + __int_as_float(p);
}
// full 16-lane-row sum: after this every lane of the 16-lane row holds the total
__device__ __forceinline__ float row16_sum(float x) {
    x = dpp_add<0xB1>(x);    // xor 1 (quad_perm 1,0,3,2)
    x = dpp_add<0x4E>(x);    // xor 2 (quad_perm 2,3,0,1)
    x = dpp_add<0x141>(x);   // xor 4 (row_half_mirror)
    x = dpp_add<0x140>(x);   // xor 8 (row_mirror)
    return x;
}

// ---------------------------------------------------------------------------
// Kernel 1: per-(b,h) tile sums of V -> partials[bh][t][d]
// ---------------------------------------------------------------------------
__global__ __launch_bounds__(256)
void dozer_chunk_sum(const float* __restrict__ V, float* __restrict__ partials) {
    const int bh = blockIdx.x;
    const int t  = blockIdx.y;
    const int b  = bh >> 3;
    const int h  = bh & 7;
    const int g  = threadIdx.x >> 6;
    const int d  = threadIdx.x & 63;
    const float* Vbh = V + (size_t)b * Lc * RHD + h * Dc;
    const int l0 = t * TL;
    float s = 0.f;
    for (int r = g; r < TL; r += 4)
        s += Vbh[(size_t)(l0 + r) * RHD + d];
    __shared__ float red[4][64];
    red[g][d] = s;
    __syncthreads();
    if (g == 0)
        partials[((size_t)bh * NT + t) * 64 + d] =
            red[0][d] + red[1][d] + red[2][d] + red[3][d];
}

// ---------------------------------------------------------------------------
// Kernel 2: main sparse-attention kernel.
// Block = (bh, tile of 16 rows), 4 waves, 4 rows per wave.
// Wave lane layout: p = lane>>4 (position slot 0..3), dd = lane&15 (d-quad).
// Position list per row l: band {0..15} (4 iters) then far {16, 65k k=1..31}
// as 32 slots with off = max(65f,16), valid iff off <= l.
// ---------------------------------------------------------------------------
__global__ __launch_bounds__(256)
void dozer_main(const float* __restrict__ Q, const float* __restrict__ K,
                const float* __restrict__ V, const float* __restrict__ partials,
                float* __restrict__ out) {
    const int bh   = blockIdx.x;
    const int t    = blockIdx.y;
    const int b    = bh >> 3;
    const int h    = bh & 7;
    const int tid  = threadIdx.x;
    const int wave = tid >> 6;
    const int lane = tid & 63;
    const int l0   = t * TL;

    const float* Qbh = Q + (size_t)b * Lc * RHD + h * Dc;
    const float* Kbh = K + (size_t)b * Lc * RHD + h * Dc;
    const float* Vbh = V + (size_t)b * Lc * RHD + h * Dc;

    __shared__ float Ptile[TL][64];   // inclusive V prefix for the tile rows
    __shared__ float red[8][64];      // [0..3]=partials-part, [4..7]=own-rows part

    // ---- prefix phase (all waves busy): wave w owns rows 4w..4w+3 ----
    {
        const int d = lane;
        float pbase = 0.f;
        if (partials) {
            const float* pb = partials + (size_t)bh * NT * 64;
            for (int c = wave; c < t; c += 4)
                pbase += pb[(size_t)c * 64 + d];
        } else {
            for (int s = wave; s < l0; s += 4)
                pbase += Vbh[(size_t)s * RHD + d];
        }
        const float* vr = Vbh + (size_t)(l0 + 4 * wave) * RHD + d;
        const float x0 = vr[0];
        const float x1 = vr[RHD];
        const float x2 = vr[2 * RHD];
        const float x3 = vr[3 * RHD];
        const float s0 = x0, s1 = s0 + x1, s2 = s1 + x2, s3 = s2 + x3;
        red[wave][d]     = pbase;
        red[4 + wave][d] = s3;
        __syncthreads();
        float base = red[0][d] + red[1][d] + red[2][d] + red[3][d];
        if (wave > 0) base += red[4][d];
        if (wave > 1) base += red[5][d];
        if (wave > 2) base += red[6][d];
        Ptile[4 * wave + 0][d] = base + s0;
        Ptile[4 * wave + 1][d] = base + s1;
        Ptile[4 * wave + 2][d] = base + s2;
        Ptile[4 * wave + 3][d] = base + s3;
        __syncthreads();
    }

    const int p  = lane >> 4;   // position slot 0..3
    const int dd = lane & 15;   // d-quad: handles d = 4*dd .. 4*dd+3

    for (int rr = 0; rr < 4; ++rr) {
        const int r = wave * 4 + rr;
        const int l = l0 + r;

        float4 q4 = *(const float4*)&Qbh[(size_t)l * RHD + dd * 4];
        q4.x *= SCALE; q4.y *= SCALE; q4.z *= SCALE; q4.w *= SCALE;

        float4 acc = make_float4(0.f, 0.f, 0.f, 0.f);
        float  den = 0.f;

        // ---- band: offsets 0..15, 4 per iteration ----
        #pragma unroll
        for (int it = 0; it < 4; ++it) {
            const int pi = p + 4 * it;
            const bool ok = (pi <= l);         // only partial for l<15 (t=0)
            int j = l - pi; if (j < 0) j = 0;
            const float* Kr = Kbh + (size_t)j * RHD + dd * 4;
            const float* Vr = Vbh + (size_t)j * RHD + dd * 4;
            const float4 k4 = *(const float4*)Kr;
            const float4 v4 = *(const float4*)Vr;
            float dot = q4.x * k4.x + q4.y * k4.y + q4.z * k4.z + q4.w * k4.w;
            dot = row16_sum(dot);
            float w = __expf(dot) - 1.f;
            w = ok ? w : 0.f;
            acc.x += w * v4.x; acc.y += w * v4.y;
            acc.z += w * v4.z; acc.w += w * v4.w;
            den += w;
        }

        // ---- far: 32 slots f=0..31, off = max(65f,16), valid iff off<=l ----
        #pragma unroll 4
        for (int it = 0; it < 8; ++it) {
            const int f   = p + 4 * it;
            int off = SP1 * f; if (off < 16) off = 16;   // f==0 -> band edge 16
            const bool ok = (off <= l);
            int j = l - off; if (j < 0) j = 0;
            const float* Kr = Kbh + (size_t)j * RHD + dd * 4;
            const float* Vr = Vbh + (size_t)j * RHD + dd * 4;
            const float4 k4 = *(const float4*)Kr;
            const float4 v4 = *(const float4*)Vr;
            float dot = q4.x * k4.x + q4.y * k4.y + q4.z * k4.z + q4.w * k4.w;
            dot = row16_sum(dot);
            float w = __expf(dot) - 1.f;
            w = ok ? w : 0.f;
            acc.x += w * v4.x; acc.y += w * v4.y;
            acc.z += w * v4.z; acc.w += w * v4.w;
            den += w;
        }

        // ---- combine across the 4 position groups (xor 16, 32) ----
        acc.x += __shfl_xor(acc.x, 16, 64); acc.x += __shfl_xor(acc.x, 32, 64);
        acc.y += __shfl_xor(acc.y, 16, 64); acc.y += __shfl_xor(acc.y, 32, 64);
        acc.z += __shfl_xor(acc.z, 16, 64); acc.z += __shfl_xor(acc.z, 32, 64);
        acc.w += __shfl_xor(acc.w, 16, 64); acc.w += __shfl_xor(acc.w, 32, 64);
        den   += __shfl_xor(den, 16, 64);   den   += __shfl_xor(den, 32, 64);

        const float inv = 1.f / ((float)(l + 1) + den);
        if (p == 0) {
            const float4 P4 = *(const float4*)&Ptile[r][dd * 4];
            float4 o;
            o.x = (P4.x + acc.x) * inv;
            o.y = (P4.y + acc.y) * inv;
            o.z = (P4.z + acc.z) * inv;
            o.w = (P4.w + acc.w) * inv;
            *(float4*)&out[((size_t)(b * Lc + l) * Hc + h) * Dc + dd * 4] = o;
        }
    }
}

// ---------------------------------------------------------------------------
extern "C" void kernel_launch(void* const* d_in, const int* in_sizes, int n_in,
                              void* d_out, int out_size, void* d_ws, size_t ws_size,
                              hipStream_t stream) {
    // inputs: 0=x (unused), 1=queries, 2=keys, 3=values, 4=attn_mask (analytic)
    const float* Q = (const float*)d_in[1];
    const float* K = (const float*)d_in[2];
    const float* V = (const float*)d_in[3];
    float* out = (float*)d_out;

    const size_t need = (size_t)Bc * Hc * NT * 64 * sizeof(float);  // 512 KB
    float* partials = (ws_size >= need) ? (float*)d_ws : nullptr;

    dim3 grid(Bc * Hc, NT);   // bh fastest: balances per-CU tile mix
    if (partials)
        dozer_chunk_sum<<<grid, 256, 0, stream>>>(V, partials);
    dozer_main<<<grid, 256, 0, stream>>>(Q, K, V, partials, out);
}

// Round 4
// 122.848 us; speedup vs baseline: 1.0598x; 1.0598x over previous
//
#include <hip/hip_runtime.h>

// Problem constants: B=2, L=2048, H=8, D=64, window=32, stride=64
#define Bc 2
#define Lc 2048
#define Hc 8
#define Dc 64
#define TL 16                 // rows per block
#define NT (Lc / TL)          // 128 tiles
#define RHD (Hc * Dc)         // 512 floats between consecutive s rows
#define SP1 65                // stride+1
#define SCALE 0.125f          // 1/sqrt(64)

// DPP-based add of a permuted copy: pure VALU, no DS traffic.
template <int CTRL>
__device__ __forceinline__ float dpp_add(float x) {
    int p = __builtin_amdgcn_update_dpp(0, __float_as_int(x), CTRL, 0xF, 0xF, true);
    return x + __int_as_float(p);
}
// 16-lane-row sum: xor1 (quad_perm), xor2 (quad_perm), xor7 (half-mirror ==
// cross-quad after quad reduce), xor15 (row mirror == cross-half). Verified R3.
__device__ __forceinline__ float row16_sum(float x) {
    x = dpp_add<0xB1>(x);
    x = dpp_add<0x4E>(x);
    x = dpp_add<0x141>(x);
    x = dpp_add<0x140>(x);
    return x;
}

// ---------------------------------------------------------------------------
// Kernel 1: per-(b,h) tile sums of V -> partials[bh][t][d]
// ---------------------------------------------------------------------------
__global__ __launch_bounds__(256)
void dozer_chunk_sum(const float* __restrict__ V, float* __restrict__ partials) {
    const int bh = blockIdx.x;
    const int t  = blockIdx.y;
    const int b  = bh >> 3;
    const int h  = bh & 7;
    const int g  = threadIdx.x >> 6;
    const int d  = threadIdx.x & 63;
    const float* Vbh = V + (size_t)b * Lc * RHD + h * Dc;
    const int l0 = t * TL;
    float s = 0.f;
    for (int r = g; r < TL; r += 4)
        s += Vbh[(size_t)(l0 + r) * RHD + d];
    __shared__ float red[4][64];
    red[g][d] = s;
    __syncthreads();
    if (g == 0)
        partials[((size_t)bh * NT + t) * 64 + d] =
            red[0][d] + red[1][d] + red[2][d] + red[3][d];
}

// ---------------------------------------------------------------------------
// Kernel 2: main kernel. Block = (bh, tile of 16 rows), 4 waves, 4 rows/wave.
// Lane layout: p = lane>>4 (slot 0..3), dd = lane&15 (d-quad).
// Unified slot list per row l:
//   it 0..3  : band offsets p+4*it (0..15)
//   it 4..   : far slot f = p+4*(it-4), off = max(65f,16)  (f==0 -> band edge 16)
// valid iff off <= l. nit = 5 + l/260 covers all f <= l/65.
// Software-pipelined depth 1: it+1 loads issued before it's compute.
// ---------------------------------------------------------------------------
__global__ __launch_bounds__(256)
void dozer_main(const float* __restrict__ Q, const float* __restrict__ K,
                const float* __restrict__ V, const float* __restrict__ partials,
                float* __restrict__ out) {
    const int bh   = blockIdx.x;
    const int t    = (NT - 1) - blockIdx.y;   // heavy tiles dispatch first
    const int b    = bh >> 3;
    const int h    = bh & 7;
    const int tid  = threadIdx.x;
    const int wave = tid >> 6;
    const int lane = tid & 63;
    const int l0   = t * TL;

    const float* Qbh = Q + (size_t)b * Lc * RHD + h * Dc;
    const float* Kbh = K + (size_t)b * Lc * RHD + h * Dc;
    const float* Vbh = V + (size_t)b * Lc * RHD + h * Dc;

    __shared__ float Ptile[TL][64];   // inclusive V prefix for the tile rows
    __shared__ float red[8][64];

    // ---- prefix phase: wave w owns rows 4w..4w+3 ----
    {
        const int d = lane;
        float pbase = 0.f;
        if (partials) {
            const float* pb = partials + (size_t)bh * NT * 64;
            #pragma unroll 4
            for (int c = wave; c < t; c += 4)
                pbase += pb[(size_t)c * 64 + d];
        } else {
            for (int s = wave; s < l0; s += 4)
                pbase += Vbh[(size_t)s * RHD + d];
        }
        const float* vr = Vbh + (size_t)(l0 + 4 * wave) * RHD + d;
        const float x0 = vr[0];
        const float x1 = vr[RHD];
        const float x2 = vr[2 * RHD];
        const float x3 = vr[3 * RHD];
        const float s0 = x0, s1 = s0 + x1, s2 = s1 + x2, s3 = s2 + x3;
        red[wave][d]     = pbase;
        red[4 + wave][d] = s3;
        __syncthreads();
        float base = red[0][d] + red[1][d] + red[2][d] + red[3][d];
        if (wave > 0) base += red[4][d];
        if (wave > 1) base += red[5][d];
        if (wave > 2) base += red[6][d];
        Ptile[4 * wave + 0][d] = base + s0;
        Ptile[4 * wave + 1][d] = base + s1;
        Ptile[4 * wave + 2][d] = base + s2;
        Ptile[4 * wave + 3][d] = base + s3;
        __syncthreads();
    }

    const int p  = lane >> 4;
    const int dd = lane & 15;

    for (int rr = 0; rr < 4; ++rr) {
        const int r = wave * 4 + rr;
        const int l = l0 + r;
        const int nit = 5 + l / 260;      // wave-uniform (rows 4w..4w+3 share l/260)

        float4 q4 = *(const float4*)&Qbh[(size_t)l * RHD + dd * 4];
        q4.x *= SCALE; q4.y *= SCALE; q4.z *= SCALE; q4.w *= SCALE;

        float4 acc = make_float4(0.f, 0.f, 0.f, 0.f);
        float  den = 0.f;

        // prologue: slot for it=0 (off = p)
        bool okc = (p <= l);
        int  j0  = l - p; if (j0 < 0) j0 = 0;
        float4 kc = *(const float4*)(Kbh + (size_t)j0 * RHD + dd * 4);
        float4 vc = *(const float4*)(Vbh + (size_t)j0 * RHD + dd * 4);

        for (int it = 0; it < nit; ++it) {
            float4 kn = kc, vn = vc;
            bool okn = false;
            if (it + 1 < nit) {
                const int it1 = it + 1;
                int off;
                if (it1 < 4) {
                    off = p + 4 * it1;
                } else {
                    off = SP1 * (p + 4 * (it1 - 4));
                    if (off < 16) off = 16;
                }
                okn = (off <= l);
                int j1 = l - off; if (j1 < 0) j1 = 0;
                kn = *(const float4*)(Kbh + (size_t)j1 * RHD + dd * 4);
                vn = *(const float4*)(Vbh + (size_t)j1 * RHD + dd * 4);
            }
            float dot = q4.x * kc.x + q4.y * kc.y + q4.z * kc.z + q4.w * kc.w;
            dot = row16_sum(dot);
            float w = __expf(dot) - 1.f;
            w = okc ? w : 0.f;
            acc.x += w * vc.x; acc.y += w * vc.y;
            acc.z += w * vc.z; acc.w += w * vc.w;
            den += w;
            kc = kn; vc = vn; okc = okn;
        }

        // combine across the 4 position groups (xor 16, 32)
        acc.x += __shfl_xor(acc.x, 16, 64); acc.x += __shfl_xor(acc.x, 32, 64);
        acc.y += __shfl_xor(acc.y, 16, 64); acc.y += __shfl_xor(acc.y, 32, 64);
        acc.z += __shfl_xor(acc.z, 16, 64); acc.z += __shfl_xor(acc.z, 32, 64);
        acc.w += __shfl_xor(acc.w, 16, 64); acc.w += __shfl_xor(acc.w, 32, 64);
        den   += __shfl_xor(den, 16, 64);   den   += __shfl_xor(den, 32, 64);

        const float inv = 1.f / ((float)(l + 1) + den);
        if (p == 0) {
            const float4 P4 = *(const float4*)&Ptile[r][dd * 4];
            float4 o;
            o.x = (P4.x + acc.x) * inv;
            o.y = (P4.y + acc.y) * inv;
            o.z = (P4.z + acc.z) * inv;
            o.w = (P4.w + acc.w) * inv;
            *(float4*)&out[((size_t)(b * Lc + l) * Hc + h) * Dc + dd * 4] = o;
        }
    }
}

// ---------------------------------------------------------------------------
extern "C" void kernel_launch(void* const* d_in, const int* in_sizes, int n_in,
                              void* d_out, int out_size, void* d_ws, size_t ws_size,
                              hipStream_t stream) {
    // inputs: 0=x (unused), 1=queries, 2=keys, 3=values, 4=attn_mask (analytic)
    const float* Q = (const float*)d_in[1];
    const float* K = (const float*)d_in[2];
    const float* V = (const float*)d_in[3];
    float* out = (float*)d_out;

    const size_t need = (size_t)Bc * Hc * NT * 64 * sizeof(float);  // 512 KB
    float* partials = (ws_size >= need) ? (float*)d_ws : nullptr;

    dim3 grid(Bc * Hc, NT);   // bh fastest: balances per-CU tile mix
    if (partials)
        dozer_chunk_sum<<<grid, 256, 0, stream>>>(V, partials);
    dozer_main<<<grid, 256, 0, stream>>>(Q, K, V, partials, out);
}

// Round 5
// 115.668 us; speedup vs baseline: 1.1256x; 1.0621x over previous
//
#include <hip/hip_runtime.h>

// Problem constants: B=2, L=2048, H=8, D=64, window=32, stride=64
#define Bc 2
#define Lc 2048
#define Hc 8
#define Dc 64
#define TL 16                 // rows per block
#define NT (Lc / TL)          // 128 tiles
#define RHD (Hc * Dc)         // 512 floats between consecutive s rows
#define SP1 65                // stride+1
#define SCALE 0.125f          // 1/sqrt(64)

// DPP-based add of a permuted copy: pure VALU, no DS traffic.
template <int CTRL>
__device__ __forceinline__ float dpp_add(float x) {
    int p = __builtin_amdgcn_update_dpp(0, __float_as_int(x), CTRL, 0xF, 0xF, true);
    return x + __int_as_float(p);
}
// 16-lane-row sum (verified R3/R4): xor1, xor2, half-mirror, mirror.
__device__ __forceinline__ float row16_sum(float x) {
    x = dpp_add<0xB1>(x);
    x = dpp_add<0x4E>(x);
    x = dpp_add<0x141>(x);
    x = dpp_add<0x140>(x);
    return x;
}

// ---------------------------------------------------------------------------
// Kernel 1: per-(b,h) tile sums of V -> partials[bh][t][d]
// ---------------------------------------------------------------------------
__global__ __launch_bounds__(256)
void dozer_chunk_sum(const float* __restrict__ V, float* __restrict__ partials) {
    const int bh = blockIdx.x;
    const int t  = blockIdx.y;
    const int b  = bh >> 3;
    const int h  = bh & 7;
    const int g  = threadIdx.x >> 6;
    const int d  = threadIdx.x & 63;
    const float* Vbh = V + (size_t)b * Lc * RHD + h * Dc;
    const int l0 = t * TL;
    float s = 0.f;
    for (int r = g; r < TL; r += 4)
        s += Vbh[(size_t)(l0 + r) * RHD + d];
    __shared__ float red[4][64];
    red[g][d] = s;
    __syncthreads();
    if (g == 0)
        partials[((size_t)bh * NT + t) * 64 + d] =
            red[0][d] + red[1][d] + red[2][d] + red[3][d];
}

// ---------------------------------------------------------------------------
// Kernel 2: main kernel. Block = (bh, tile of 16 rows), 4 waves, 4 rows/wave.
// Lane layout: p = lane>>4 (slot 0..3), dd = lane&15 (d-quad).
// Band (offsets 0..16) is served from LDS (staged once per block: rows
// [l0-16, l0+15]); far list (off = 65f, f=1..l/65) from global with a
// depth-2 rotating prefetch issued BEFORE the band phase (band compute
// covers the far-load latency).
// LDS: Kband 8K + Vband 8K + Ptile 4K = 20480 B -> 8 blocks/CU (160 KiB).
// ---------------------------------------------------------------------------
__global__ __launch_bounds__(256)
void dozer_main(const float* __restrict__ Q, const float* __restrict__ K,
                const float* __restrict__ V, const float* __restrict__ partials,
                float* __restrict__ out) {
    const int bh   = blockIdx.x;
    const int t    = (NT - 1) - blockIdx.y;   // heavy tiles first
    const int b    = bh >> 3;
    const int h    = bh & 7;
    const int tid  = threadIdx.x;
    const int wave = tid >> 6;
    const int lane = tid & 63;
    const int l0   = t * TL;

    const float* Qbh = Q + (size_t)b * Lc * RHD + h * Dc;
    const float* Kbh = K + (size_t)b * Lc * RHD + h * Dc;
    const float* Vbh = V + (size_t)b * Lc * RHD + h * Dc;

    __shared__ float Kband[32][64];
    __shared__ float Vband[32][64];
    __shared__ float Ptile[TL][64];
    // red aliases the first 2 KB of Kband: used only in the prefix phase,
    // fully consumed before staging overwrites it.
    float (*red)[64] = (float(*)[64])Kband;

    // ---- prefix phase: wave w owns rows 4w..4w+3 ----
    {
        const int d = lane;
        float pbase = 0.f;
        if (partials) {
            const float* pb = partials + (size_t)bh * NT * 64;
            #pragma unroll 4
            for (int c = wave; c < t; c += 4)
                pbase += pb[(size_t)c * 64 + d];
        } else {
            for (int s = wave; s < l0; s += 4)
                pbase += Vbh[(size_t)s * RHD + d];
        }
        const float* vr = Vbh + (size_t)(l0 + 4 * wave) * RHD + d;
        const float x0 = vr[0];
        const float x1 = vr[RHD];
        const float x2 = vr[2 * RHD];
        const float x3 = vr[3 * RHD];
        const float s0 = x0, s1 = s0 + x1, s2 = s1 + x2, s3 = s2 + x3;
        red[wave][d]     = pbase;
        red[4 + wave][d] = s3;
        __syncthreads();
        float base = red[0][d] + red[1][d] + red[2][d] + red[3][d];
        if (wave > 0) base += red[4][d];
        if (wave > 1) base += red[5][d];
        if (wave > 2) base += red[6][d];
        Ptile[4 * wave + 0][d] = base + s0;
        Ptile[4 * wave + 1][d] = base + s1;
        Ptile[4 * wave + 2][d] = base + s2;
        Ptile[4 * wave + 3][d] = base + s3;
        __syncthreads();   // everyone done with red before staging clobbers it
    }

    // ---- stage band rows [l0-16, l0+15] of K and V into LDS ----
    {
        const int i  = tid >> 4;            // 0..15
        const int c4 = (tid & 15) * 4;
        #pragma unroll
        for (int rnd = 0; rnd < 2; ++rnd) {
            const int ii = i + 16 * rnd;    // 0..31
            int j = l0 - 16 + ii; if (j < 0) j = 0;   // t=0 garbage rows masked later
            *(float4*)&Kband[ii][c4] = *(const float4*)(Kbh + (size_t)j * RHD + c4);
            *(float4*)&Vband[ii][c4] = *(const float4*)(Vbh + (size_t)j * RHD + c4);
        }
        __syncthreads();
    }

    const int p  = lane >> 4;
    const int dd = lane & 15;

    for (int rr = 0; rr < 4; ++rr) {
        const int r = wave * 4 + rr;
        const int l = l0 + r;
        const int nk   = l / SP1;            // far offsets 65f, f = 1..nk
        const int nfar = (nk + 3) >> 2;      // far iterations (4 slots each)

        float4 q4 = *(const float4*)&Qbh[(size_t)l * RHD + dd * 4];
        q4.x *= SCALE; q4.y *= SCALE; q4.z *= SCALE; q4.w *= SCALE;

        float4 acc = make_float4(0.f, 0.f, 0.f, 0.f);
        float  den = 0.f;

        auto farload = [&](float4& k4, float4& v4, int m) {
            const int f = 1 + p + 4 * m;
            int j = l - SP1 * f; if (j < 0) j = 0;
            k4 = *(const float4*)(Kbh + (size_t)j * RHD + dd * 4);
            v4 = *(const float4*)(Vbh + (size_t)j * RHD + dd * 4);
        };
        auto farstep = [&](const float4& k4, const float4& v4, int m) {
            const int f = 1 + p + 4 * m;
            const bool ok = (f <= nk);
            float dot = q4.x * k4.x + q4.y * k4.y + q4.z * k4.z + q4.w * k4.w;
            dot = row16_sum(dot);
            float w = __expf(dot) - 1.f;
            w = ok ? w : 0.f;
            acc.x += w * v4.x; acc.y += w * v4.y;
            acc.z += w * v4.z; acc.w += w * v4.w;
            den += w;
        };

        // far prologue: issue global loads now; band phase below covers latency
        float4 kA = make_float4(0.f,0.f,0.f,0.f), vA = kA, kB = kA, vB = kA;
        if (nfar > 0) farload(kA, vA, 0);
        if (nfar > 1) farload(kB, vB, 1);

        // ---- band from LDS: offsets 0..15 ----
        #pragma unroll
        for (int it = 0; it < 4; ++it) {
            const int off = p + 4 * it;
            const int idx = r + 16 - off;          // in [1, 31]
            const bool ok = (off <= l);
            const float4 k4 = *(const float4*)&Kband[idx][dd * 4];
            const float4 v4 = *(const float4*)&Vband[idx][dd * 4];
            float dot = q4.x * k4.x + q4.y * k4.y + q4.z * k4.z + q4.w * k4.w;
            dot = row16_sum(dot);
            float w = __expf(dot) - 1.f;
            w = ok ? w : 0.f;
            acc.x += w * v4.x; acc.y += w * v4.y;
            acc.z += w * v4.z; acc.w += w * v4.w;
            den += w;
        }
        {   // band edge offset 16 (slot p==0 only), idx = r >= 0
            const bool ok = (p == 0) && (l >= 16);
            const float4 k4 = *(const float4*)&Kband[r][dd * 4];
            const float4 v4 = *(const float4*)&Vband[r][dd * 4];
            float dot = q4.x * k4.x + q4.y * k4.y + q4.z * k4.z + q4.w * k4.w;
            dot = row16_sum(dot);
            float w = __expf(dot) - 1.f;
            w = ok ? w : 0.f;
            acc.x += w * v4.x; acc.y += w * v4.y;
            acc.z += w * v4.z; acc.w += w * v4.w;
            den += w;
        }

        // ---- far loop: depth-2 rotating prefetch ----
        int m = 0;
        for (; m + 1 < nfar; m += 2) {
            farstep(kA, vA, m);
            if (m + 2 < nfar) farload(kA, vA, m + 2);
            farstep(kB, vB, m + 1);
            if (m + 3 < nfar) farload(kB, vB, m + 3);
        }
        if (m < nfar) farstep(kA, vA, m);

        // ---- combine across the 4 position groups (xor 16, 32) ----
        acc.x += __shfl_xor(acc.x, 16, 64); acc.x += __shfl_xor(acc.x, 32, 64);
        acc.y += __shfl_xor(acc.y, 16, 64); acc.y += __shfl_xor(acc.y, 32, 64);
        acc.z += __shfl_xor(acc.z, 16, 64); acc.z += __shfl_xor(acc.z, 32, 64);
        acc.w += __shfl_xor(acc.w, 16, 64); acc.w += __shfl_xor(acc.w, 32, 64);
        den   += __shfl_xor(den, 16, 64);   den   += __shfl_xor(den, 32, 64);

        const float inv = 1.f / ((float)(l + 1) + den);
        if (p == 0) {
            const float4 P4 = *(const float4*)&Ptile[r][dd * 4];
            float4 o;
            o.x = (P4.x + acc.x) * inv;
            o.y = (P4.y + acc.y) * inv;
            o.z = (P4.z + acc.z) * inv;
            o.w = (P4.w + acc.w) * inv;
            *(float4*)&out[((size_t)(b * Lc + l) * Hc + h) * Dc + dd * 4] = o;
        }
    }
}

// ---------------------------------------------------------------------------
extern "C" void kernel_launch(void* const* d_in, const int* in_sizes, int n_in,
                              void* d_out, int out_size, void* d_ws, size_t ws_size,
                              hipStream_t stream) {
    // inputs: 0=x (unused), 1=queries, 2=keys, 3=values, 4=attn_mask (analytic)
    const float* Q = (const float*)d_in[1];
    const float* K = (const float*)d_in[2];
    const float* V = (const float*)d_in[3];
    float* out = (float*)d_out;

    const size_t need = (size_t)Bc * Hc * NT * 64 * sizeof(float);  // 512 KB
    float* partials = (ws_size >= need) ? (float*)d_ws : nullptr;

    dim3 grid(Bc * Hc, NT);   // bh fastest: balances per-CU tile mix
    if (partials)
        dozer_chunk_sum<<<grid, 256, 0, stream>>>(V, partials);
    dozer_main<<<grid, 256, 0, stream>>>(Q, K, V, partials, out);
}